// Round 10
// baseline (378.191 us; speedup 1.0000x reference)
//
#include <hip/hip_runtime.h>

// SelfAttention: B=4, L=4096, H=256, fp32 in/out.
// Round 10: occupancy x1.5 with frozen numerics (r9 error budget: absmax 0.625
// of 1.01 — do not touch precision).
//  - attn: split-K x3 across blocks (grid 768 = 3 blocks/CU, macros 22/21/21),
//    launch_bounds(256,3). Fits now: r9 measured 112 VGPR / 41 KB LDS vs the
//    (256,3) caps of 170 / 53 KB (r5's spill was the 230-reg split-bf16 set).
//  - qkv: single-plane W staging (Wh stage -> ah*bh + al*bh; Wl stage ->
//    ah*bl) halves W LDS to 32 KB; separate 9 KB scratch -> 41 KB -> (256,3).
//  - merge: 3 partials.
// Carried: fp16 attention core (1-MFMA QK), DMA-dbuf K, DPP softmax,
// alpha-skip, uniform bases, 64-key macro softmax, split-bf16 3-product qkv.

typedef __bf16 bf16x8 __attribute__((ext_vector_type(8)));
typedef _Float16 f16x8 __attribute__((ext_vector_type(8)));
typedef _Float16 f16x4 __attribute__((ext_vector_type(4)));
typedef float floatx4 __attribute__((ext_vector_type(4)));

#define MFMA16B(a, b, c) __builtin_amdgcn_mfma_f32_16x16x32_bf16(a, b, c, 0, 0, 0)
#define MFMA16F(a, b, c) __builtin_amdgcn_mfma_f32_16x16x32_f16(a, b, c, 0, 0, 0)
#define GLOAD_LDS16(g, l)                                                  \
  __builtin_amdgcn_global_load_lds(                                        \
      (const __attribute__((address_space(1))) void *)(g),                 \
      (__attribute__((address_space(3))) void *)(l), 16, 0, 0)

#define HID 256
#define LSEQ 4096
#define NB 4
#define NTOK (NB * LSEQ)             // 16384
#define PLANE ((size_t)NTOK * HID)   // 4,194,304 elements
#define QSCALE 0.09016844005556021f  // log2(e)/16 ; softmax uses exp2
#define NKS 3

// Layouts:
//  Wht/Wlt [3][n][h] row-major hi/lo bf16 weights (transposed).
//  Qf [tok][h] row-major fp16 (pre-scaled by QSCALE).
//  Kf (32-key tiles, T = tok>>5, 512 tiles): [T][nt(2)][kc(8)][lane(64)][j(8)]
//    fp16, tile stride 8192 el (16 KB).
//  Vf (32-key tiles): [T][dt(16)][lane][j] fp16, tile stride 8192 el.

__device__ __forceinline__ void split_bf16(float v, __bf16 &h, __bf16 &l) {
  h = (__bf16)v;
  l = (__bf16)(v - (float)h);
}

// DPP 16-lane-row butterfly reductions (VALU, no LDS pipe).
template <int N>
__device__ __forceinline__ float dpp_ror(float v) {
  return __builtin_bit_cast(float,
      __builtin_amdgcn_update_dpp(0, __builtin_bit_cast(int, v),
                                  0x120 + N, 0xf, 0xf, true));
}
__device__ __forceinline__ float row_sum16(float v) {
  v += dpp_ror<1>(v);
  v += dpp_ror<2>(v);
  v += dpp_ror<4>(v);
  v += dpp_ror<8>(v);
  return v;
}
__device__ __forceinline__ float row_max16(float v) {
  v = fmaxf(v, dpp_ror<1>(v));
  v = fmaxf(v, dpp_ror<2>(v));
  v = fmaxf(v, dpp_ror<4>(v));
  v = fmaxf(v, dpp_ror<8>(v));
  return v;
}

// ---------------------------------------------------------------------------
// Kernel 1: transpose + hi/lo-split weights -> Wht/Wlt [3][n][h] row-major.
// grid (3, 8): one 32-h-row slab per block.
// ---------------------------------------------------------------------------
__global__ __launch_bounds__(256) void wsplit(const float *__restrict__ Wq,
                                              const float *__restrict__ Wk,
                                              const float *__restrict__ Wv,
                                              __bf16 *__restrict__ Wht,
                                              __bf16 *__restrict__ Wlt) {
  __shared__ float tile[32][256];
  const int wsel = blockIdx.x;
  const int hb = blockIdx.y;
  const float *W = (wsel == 0) ? Wq : (wsel == 1) ? Wk : Wv;
  __bf16 *oh = Wht + wsel * HID * HID;
  __bf16 *ol = Wlt + wsel * HID * HID;
  const int t = threadIdx.x;
  #pragma unroll
  for (int p = 0; p < 8; ++p) {
    int r = p * 4 + (t >> 6);
    int c = (t & 63) * 4;
    *(floatx4 *)&tile[r][c] = *(const floatx4 *)&W[(hb * 32 + r) * HID + c];
  }
  __syncthreads();
  #pragma unroll
  for (int q = 0; q < 4; ++q) {
    int n = q * 64 + (t >> 2);
    int hs = (t & 3) * 8;
    bf16x8 hh, ll;
    #pragma unroll
    for (int i = 0; i < 8; ++i) {
      float v = tile[hs + i][n];
      __bf16 h, l;
      split_bf16(v, h, l);
      hh[i] = h; ll[i] = l;
    }
    *(bf16x8 *)&oh[n * HID + hb * 32 + hs] = hh;
    *(bf16x8 *)&ol[n * HID + hb * 32 + hs] = ll;
  }
}

// ---------------------------------------------------------------------------
// Kernel 2: QKV projection, split-bf16 3-product math (unchanged numerics).
// Single-plane W staging: per w, stage Wh (32 KB) -> ah*bh + al*bh products;
// stage Wl -> ah*bl. Separate 9 KB fp16 scratch for epilogue transposes.
// LDS 41 KB, launch_bounds(256,3) = 3 blocks/CU. W chunks reg-prefetched one
// stage ahead. grid = (256 m-tiles, 4 col-tiles of 64).
// ---------------------------------------------------------------------------
__global__ __launch_bounds__(256, 3) void qkv_proj(const float *__restrict__ X,
                                                   const __bf16 *__restrict__ Wht,
                                                   const __bf16 *__restrict__ Wlt,
                                                   _Float16 *__restrict__ Qf,
                                                   _Float16 *__restrict__ Kf,
                                                   _Float16 *__restrict__ Vf) {
  __shared__ __bf16 WS[64 * 256];       // 32 KB, one plane at a time
  __shared__ _Float16 Tf[64 * 72];      // 9 KB epilogue transpose scratch

  const int mtile = blockIdx.x;
  const int col0 = blockIdx.y * 64;
  const int tid = threadIdx.x;
  const int w4 = tid >> 6;
  const int lane = tid & 63;
  const int quad = lane >> 4;
  const int ln = lane & 15;
  const int arow = mtile * 64 + w4 * 16 + ln;

  bf16x8 ah[8], al[8];
  #pragma unroll
  for (int kc = 0; kc < 8; ++kc) {
    const float *xp = X + (size_t)arow * HID + kc * 32 + quad * 8;
    floatx4 x0 = *(const floatx4 *)xp;
    floatx4 x1 = *(const floatx4 *)(xp + 4);
    #pragma unroll
    for (int j = 0; j < 4; ++j) {
      __bf16 h, l;
      split_bf16(x0[j], h, l); ah[kc][j] = h; al[kc][j] = l;
      split_bf16(x1[j], h, l); ah[kc][4 + j] = h; al[kc][4 + j] = l;
    }
  }

  const int srow = tid >> 2;
  const int sseg = tid & 3;
  const size_t wrowbase = (size_t)(col0 + srow) * HID;

  // Prefetch stage 0 (w=0 hi plane).
  bf16x8 pw[8];
  #pragma unroll
  for (int j = 0; j < 8; ++j)
    pw[j] = *(const bf16x8 *)&Wht[wrowbase + (j * 4 + sseg) * 8];

  for (int w = 0; w < 3; ++w) {
    floatx4 acc[4] = {};
    // ---- stage A: hi plane -> ah*bh + al*bh ----
    __syncthreads();  // prev stage reads done
    #pragma unroll
    for (int j = 0; j < 8; ++j) {
      const int chunk = j * 4 + sseg;
      *(bf16x8 *)&WS[srow * 256 + ((chunk ^ (srow & 7)) << 3)] = pw[j];
    }
    __syncthreads();
    // prefetch stage B (lo plane, same w)
    {
      const size_t wbase = (size_t)w * HID * HID + wrowbase;
      #pragma unroll
      for (int j = 0; j < 8; ++j)
        pw[j] = *(const bf16x8 *)&Wlt[wbase + (j * 4 + sseg) * 8];
    }
    #pragma unroll
    for (int kc = 0; kc < 8; ++kc) {
      #pragma unroll
      for (int nt = 0; nt < 4; ++nt) {
        const int a = (nt * 16 + ln) * 256 + (((kc * 4 + quad) ^ (ln & 7)) << 3);
        bf16x8 bh = *(const bf16x8 *)&WS[a];
        acc[nt] = MFMA16B(ah[kc], bh, acc[nt]);
        acc[nt] = MFMA16B(al[kc], bh, acc[nt]);
      }
    }
    // ---- stage B: lo plane -> ah*bl ----
    __syncthreads();
    #pragma unroll
    for (int j = 0; j < 8; ++j) {
      const int chunk = j * 4 + sseg;
      *(bf16x8 *)&WS[srow * 256 + ((chunk ^ (srow & 7)) << 3)] = pw[j];
    }
    __syncthreads();
    // prefetch next w's hi plane
    if (w < 2) {
      const size_t wbase = (size_t)(w + 1) * HID * HID + wrowbase;
      #pragma unroll
      for (int j = 0; j < 8; ++j)
        pw[j] = *(const bf16x8 *)&Wht[wbase + (j * 4 + sseg) * 8];
    }
    #pragma unroll
    for (int kc = 0; kc < 8; ++kc) {
      #pragma unroll
      for (int nt = 0; nt < 4; ++nt) {
        const int a = (nt * 16 + ln) * 256 + (((kc * 4 + quad) ^ (ln & 7)) << 3);
        bf16x8 bl = *(const bf16x8 *)&WS[a];
        acc[nt] = MFMA16B(ah[kc], bl, acc[nt]);
      }
    }

    // ---- epilogues (C/D: col = lane&15, row = quad*4 + reg) ----
    if (w == 0) {
      #pragma unroll
      for (int nt = 0; nt < 4; ++nt) {
        #pragma unroll
        for (int r = 0; r < 4; ++r) {
          const int orow = mtile * 64 + w4 * 16 + quad * 4 + r;
          const int ocol = col0 + nt * 16 + ln;
          Qf[(size_t)orow * HID + ocol] = (_Float16)(acc[nt][r] * QSCALE);
        }
      }
    } else if (w == 1) {
      #pragma unroll
      for (int nt = 0; nt < 4; ++nt) {
        #pragma unroll
        for (int r = 0; r < 4; ++r) {
          const int tok_l = w4 * 16 + quad * 4 + r;
          Tf[tok_l * 72 + nt * 16 + ln] = (_Float16)acc[nt][r];
        }
      }
      __syncthreads();
      #pragma unroll
      for (int i = 0; i < 2; ++i) {     // 512 chunks of 16B
        const int c = i * 256 + tid;
        const int lane_f = c & 63;
        const int ntf = (c >> 6) & 1;
        const int kcL = (c >> 7) & 1;
        const int t2 = (c >> 8) & 1;
        const int qf = lane_f >> 4;
        const int lnf = lane_f & 15;
        const int tok_l = t2 * 32 + ntf * 16 + lnf;
        f16x8 v = *(const f16x8 *)&Tf[tok_l * 72 + kcL * 32 + qf * 8];
        const int T = mtile * 2 + t2;
        const int kc = (col0 >> 5) + kcL;
        *(f16x8 *)&Kf[(size_t)T * 8192 + ((ntf * 8 + kc) * 64 + lane_f) * 8] = v;
      }
      // next w's stage-A sync orders Tf reads before rewrite
    } else {
      #pragma unroll
      for (int nt = 0; nt < 4; ++nt) {
        #pragma unroll
        for (int r = 0; r < 4; ++r) {
          const int tok_l = w4 * 16 + quad * 4 + r;
          Tf[(nt * 16 + ln) * 72 + tok_l] = (_Float16)acc[nt][r];
        }
      }
      __syncthreads();
      #pragma unroll
      for (int i = 0; i < 2; ++i) {     // 512 chunks of 16B
        const int c = i * 256 + tid;
        const int lane_f = c & 63;
        const int dtL = (c >> 6) & 3;
        const int t2 = (c >> 8) & 1;
        const int qf = lane_f >> 4;
        const int lnf = lane_f & 15;
        f16x8 v = *(const f16x8 *)&Tf[(dtL * 16 + lnf) * 72 + t2 * 32 + qf * 8];
        const int T = mtile * 2 + t2;
        const int dt = (col0 >> 4) + dtL;
        *(f16x8 *)&Vf[(size_t)(T * 16 + dt) * 512 + lane_f * 8] = v;
      }
    }
  }
  // w==1 epilogue's Tf reads vs w==2's Tf writes are ordered by w==2 stage-A's
  // first __syncthreads.
}

// ---------------------------------------------------------------------------
// Kernel 3: flash attention, fp16 core, split-K x3.
// grid = 768 (qt = bx/3, ks = bx%3; macros 22/21/21 of 64 keys), 256 thr,
// 3 blocks/CU (LDS 41 KB, regs ~112 < 170 cap). Per macro: DMA-dbuf KS0/KS1,
// fp16 QK, ONE softmax/P-round-trip/rescale; V direct from global.
// ---------------------------------------------------------------------------
__global__ __launch_bounds__(256, 3) void attn(const _Float16 *__restrict__ Qf,
                                               const _Float16 *__restrict__ Kf,
                                               const _Float16 *__restrict__ Vf,
                                               _Float16 *__restrict__ Op,
                                               float *__restrict__ Mp,
                                               float *__restrict__ Lp) {
  __shared__ _Float16 KS0[8192];
  __shared__ _Float16 KS1[8192];
  __shared__ _Float16 PsS[4 * 16 * 72];

  const int bx = blockIdx.x;
  const int ks = bx % NKS;
  const int qt = bx / NKS;
  const int b = qt >> 6;
  const int qtl = qt & 63;
  const int tid = threadIdx.x;
  const int w4 = tid >> 6;
  const int lane = tid & 63;
  const int quad = lane >> 4;
  const int ln = lane & 15;

  const int MST[NKS + 1] = {0, 22, 43, 64};  // 64-key macro boundaries
  const int ts = MST[ks];
  const int nmac = MST[ks + 1] - ts;

  const int qtok = b * LSEQ + qtl * 64 + w4 * 16 + ln;
  f16x8 q[8];
  #pragma unroll
  for (int kc = 0; kc < 8; ++kc)
    q[kc] = *(const f16x8 *)&Qf[(size_t)qtok * HID + kc * 32 + quad * 8];

  // Uniform bases (SALU) + fixed per-lane offsets.
  const _Float16 *kuni = Kf + ((size_t)b * 128 + ts * 2) * 8192;
  const _Float16 *vuni = Vf + ((size_t)b * 128 + ts * 2) * 8192;
  const int koff = tid * 8;
  const int voff = lane * 8;

  // Prologue: DMA tile 0 -> KS0.
  #pragma unroll
  for (int i = 0; i < 4; ++i)
    GLOAD_LDS16(kuni + i * 2048 + koff, &KS0[i * 2048 + koff]);

  float m[4] = {-1e30f, -1e30f, -1e30f, -1e30f};
  float l[4] = {0.f, 0.f, 0.f, 0.f};
  floatx4 o[16] = {};

  for (int jm = 0; jm < nmac; ++jm) {
    floatx4 s[4];
    // ---------- tile A (32 keys) from KS0 ----------
    __syncthreads();  // drains KS0's DMA; all waves done reading KS1 (prev macro)
    {
      const _Float16 *src = kuni + (size_t)(2 * jm + 1) * 8192 + koff;
      #pragma unroll
      for (int i = 0; i < 4; ++i)
        GLOAD_LDS16(src + i * 2048, &KS1[i * 2048 + koff]);
    }
    {
      floatx4 pa[2] = {}, pb[2] = {};
      #pragma unroll
      for (int nt = 0; nt < 2; ++nt)
        #pragma unroll
        for (int kc = 0; kc < 4; ++kc) {
          pa[nt] = MFMA16F(q[kc], *(const f16x8 *)(KS0 + (nt * 8 + kc) * 512 + voff), pa[nt]);
          pb[nt] = MFMA16F(q[4 + kc], *(const f16x8 *)(KS0 + (nt * 8 + 4 + kc) * 512 + voff), pb[nt]);
        }
      s[0] = pa[0] + pb[0];
      s[1] = pa[1] + pb[1];
    }
    // ---------- tile B (next 32 keys) from KS1 ----------
    __syncthreads();  // drains KS1's DMA; all waves done reading KS0
    if (jm < nmac - 1) {
      const _Float16 *src = kuni + (size_t)(2 * jm + 2) * 8192 + koff;
      #pragma unroll
      for (int i = 0; i < 4; ++i)
        GLOAD_LDS16(src + i * 2048, &KS0[i * 2048 + koff]);
    }
    const _Float16 *va = vuni + (size_t)(2 * jm) * 8192;
    const _Float16 *vbp = vuni + (size_t)(2 * jm + 1) * 8192;
    f16x8 vb0[8];
    #pragma unroll
    for (int dt = 0; dt < 8; ++dt)
      vb0[dt] = *(const f16x8 *)(va + dt * 512 + voff);
    {
      floatx4 pa[2] = {}, pb[2] = {};
      #pragma unroll
      for (int nt = 0; nt < 2; ++nt)
        #pragma unroll
        for (int kc = 0; kc < 4; ++kc) {
          pa[nt] = MFMA16F(q[kc], *(const f16x8 *)(KS1 + (nt * 8 + kc) * 512 + voff), pa[nt]);
          pb[nt] = MFMA16F(q[4 + kc], *(const f16x8 *)(KS1 + (nt * 8 + 4 + kc) * 512 + voff), pb[nt]);
        }
      s[2] = pa[0] + pb[0];
      s[3] = pa[1] + pb[1];
    }
    f16x8 vb1[8];
    #pragma unroll
    for (int dt = 0; dt < 8; ++dt)
      vb1[dt] = *(const f16x8 *)(va + (8 + dt) * 512 + voff);

    // ---------- softmax over 64 keys (base-2, DPP) ----------
    float alpha[4];
    #pragma unroll
    for (int r = 0; r < 4; ++r) {
      const float tmax = row_max16(
          fmaxf(fmaxf(s[0][r], s[1][r]), fmaxf(s[2][r], s[3][r])));
      const float mn = fmaxf(m[r], tmax);
      const float al = exp2f(m[r] - mn);
      const float p0 = exp2f(s[0][r] - mn);
      const float p1 = exp2f(s[1][r] - mn);
      const float p2 = exp2f(s[2][r] - mn);
      const float p3 = exp2f(s[3][r] - mn);
      s[0][r] = p0; s[1][r] = p1; s[2][r] = p2; s[3][r] = p3;
      const float rs = row_sum16((p0 + p1) + (p2 + p3));
      l[r] = l[r] * al + rs;
      m[r] = mn;
      alpha[r] = al;
    }

    // ---------- P write (C-layout -> A-layout via per-wave LDS) ----------
    _Float16 *ps = PsS + w4 * 16 * 72;
    #pragma unroll
    for (int nt = 0; nt < 4; ++nt)
      #pragma unroll
      for (int r = 0; r < 4; ++r)
        ps[(quad * 4 + r) * 72 + nt * 16 + ln] = (_Float16)s[nt][r];

    // ---------- O rescale (alpha-skip) ----------
    const float amin = fminf(fminf(alpha[0], alpha[1]), fminf(alpha[2], alpha[3]));
    if (__any(amin < 1.0f)) {
      #pragma unroll
      for (int dt = 0; dt < 16; ++dt) {
        o[dt][0] *= alpha[0]; o[dt][1] *= alpha[1];
        o[dt][2] *= alpha[2]; o[dt][3] *= alpha[3];
      }
    }

    const f16x8 paA = *(const f16x8 *)&ps[ln * 72 + quad * 8];
    const f16x8 paB = *(const f16x8 *)&ps[ln * 72 + 32 + quad * 8];

    // ---------- O += P V (two 32-key halves) ----------
    #pragma unroll
    for (int dt = 0; dt < 8; ++dt) o[dt] = MFMA16F(paA, vb0[dt], o[dt]);
    f16x8 vb2[8];
    #pragma unroll
    for (int dt = 0; dt < 8; ++dt)
      vb2[dt] = *(const f16x8 *)(vbp + dt * 512 + voff);
    #pragma unroll
    for (int dt = 0; dt < 8; ++dt) o[8 + dt] = MFMA16F(paA, vb1[dt], o[8 + dt]);
    f16x8 vb3[8];
    #pragma unroll
    for (int dt = 0; dt < 8; ++dt)
      vb3[dt] = *(const f16x8 *)(vbp + (8 + dt) * 512 + voff);
    #pragma unroll
    for (int dt = 0; dt < 8; ++dt) o[dt] = MFMA16F(paB, vb2[dt], o[dt]);
    #pragma unroll
    for (int dt = 0; dt < 8; ++dt) o[8 + dt] = MFMA16F(paB, vb3[dt], o[8 + dt]);
  }

  const int rowbase = b * LSEQ + qtl * 64 + w4 * 16 + quad * 4;
  #pragma unroll
  for (int dt = 0; dt < 16; ++dt)
    #pragma unroll
    for (int r = 0; r < 4; ++r)
      Op[(size_t)ks * PLANE + (size_t)(rowbase + r) * HID + dt * 16 + ln] =
          (_Float16)o[dt][r];
  if (ln == 0) {
    #pragma unroll
    for (int r = 0; r < 4; ++r) {
      Mp[ks * NTOK + rowbase + r] = m[r];
      Lp[ks * NTOK + rowbase + r] = l[r];
    }
  }
}

// ---------------------------------------------------------------------------
// Kernel 4: split-K merge over 3 fp16 partials.
// ---------------------------------------------------------------------------
__global__ __launch_bounds__(256) void merge(const _Float16 *__restrict__ Op,
                                             const float *__restrict__ Mp,
                                             const float *__restrict__ Lp,
                                             float *__restrict__ Out) {
  const int row = blockIdx.x * 4 + (threadIdx.x >> 6);
  const int c = (threadIdx.x & 63) * 4;
  float M = -1e30f;
  #pragma unroll
  for (int i = 0; i < NKS; ++i) M = fmaxf(M, Mp[i * NTOK + row]);
  float L = 0.f;
  float e[NKS];
  #pragma unroll
  for (int i = 0; i < NKS; ++i) {
    e[i] = exp2f(Mp[i * NTOK + row] - M);
    L += Lp[i * NTOK + row] * e[i];
  }
  const float invL = 1.0f / L;
  floatx4 out = {};
  #pragma unroll
  for (int i = 0; i < NKS; ++i) {
    const float w = e[i] * invL;
    f16x4 a = *(const f16x4 *)&Op[i * PLANE + (size_t)row * HID + c];
    #pragma unroll
    for (int j = 0; j < 4; ++j) out[j] += w * (float)a[j];
  }
  *(floatx4 *)&Out[(size_t)row * HID + c] = out;
}

// ---------------------------------------------------------------------------
extern "C" void kernel_launch(void *const *d_in, const int *in_sizes, int n_in,
                              void *d_out, int out_size, void *d_ws, size_t ws_size,
                              hipStream_t stream) {
  const float *X = (const float *)d_in[0];
  const float *Wq = (const float *)d_in[1];
  const float *Wk = (const float *)d_in[2];
  const float *Wv = (const float *)d_in[3];
  // d_in[4] = lengths (unused by reference)

  // Workspace (2-byte elements). ~51.5 MB total.
  _Float16 *ws = (_Float16 *)d_ws;
  _Float16 *Qf = ws;                          // [16384][256] row-major fp16
  _Float16 *Kf = Qf + PLANE;                  // 32-key frag-linear fp16
  _Float16 *Vf = Kf + PLANE;                  // 32-key frag-linear fp16
  __bf16 *Wht = (__bf16 *)(Vf + PLANE);       // [3][256][256] bf16 hi
  __bf16 *Wlt = Wht + 3 * HID * HID;          // bf16 lo
  _Float16 *Op = (_Float16 *)(Wlt + 3 * HID * HID);  // [3][16384][256] fp16
  float *Mp = (float *)(Op + (size_t)NKS * PLANE);   // [3][16384]
  float *Lp = Mp + NKS * NTOK;                       // [3][16384]

  wsplit<<<dim3(3, 8), 256, 0, stream>>>(Wq, Wk, Wv, Wht, Wlt);
  qkv_proj<<<dim3(256, 4), 256, 0, stream>>>(X, Wht, Wlt, Qf, Kf, Vf);
  attn<<<256 * NKS, 256, 0, stream>>>(Qf, Kf, Vf, Op, Mp, Lp);
  merge<<<NTOK / 4, 256, 0, stream>>>(Op, Mp, Lp, (float *)d_out);
}